// Round 3
// baseline (298.082 us; speedup 1.0000x reference)
//
#include <hip/hip_runtime.h>

typedef __attribute__((ext_vector_type(8))) short short8;
typedef __attribute__((ext_vector_type(4))) float f32x4;

__device__ __forceinline__ unsigned short f2bf(float f){
  unsigned u = __float_as_uint(f);
  return (unsigned short)((u + 0x7fffu + ((u >> 16) & 1u)) >> 16);
}
__device__ __forceinline__ float bf2f(unsigned short b){
  return __uint_as_float(((unsigned)b) << 16);
}
__device__ __forceinline__ float sigf(float v){
  return __builtin_amdgcn_rcpf(1.0f + __builtin_amdgcn_exp2f(v * -1.44269504088896341f));
}
__device__ __forceinline__ float tanhf_fast(float v){
  float e = __builtin_amdgcn_exp2f(v * 2.88539008177792681f);
  return (e - 1.0f) * __builtin_amdgcn_rcpf(e + 1.0f);
}

// ---------------- weight conversion: fp32 -> bf16 in ws ----------------
// wgt layout (u16 elems):
//   whhT_b [384*128]  @0
//   W1b    [128*96]   @49152   (96 = 68 padded, zeros)
//   W2b    [128*128]  @61440
//   Wf1b   [256*1152] @77824
//   Wf2b   [128*256]  @372736
//   Wf3b   [64*128]   @405504
//   whhN_b [192*64]   @413696
__global__ __launch_bounds__(256) void k_prep(
    const float* __restrict__ Whh_t, const float* __restrict__ W1,
    const float* __restrict__ W2,    const float* __restrict__ Wf1,
    const float* __restrict__ Wf2,   const float* __restrict__ Wf3,
    const float* __restrict__ Whh_n,
    unsigned short* __restrict__ wgt)
{
  int i = blockIdx.x * 256 + threadIdx.x;
  if (i < 49152){ wgt[i] = f2bf(Whh_t[i]); return; }
  i -= 49152;
  if (i < 12288){ int r = i / 96, c = i % 96;
    wgt[49152 + i] = (c < 68) ? f2bf(W1[r*68 + c]) : (unsigned short)0; return; }
  i -= 12288;
  if (i < 16384){ wgt[61440 + i] = f2bf(W2[i]); return; }
  i -= 16384;
  if (i < 294912){ wgt[77824 + i] = f2bf(Wf1[i]); return; }
  i -= 294912;
  if (i < 32768){ wgt[372736 + i] = f2bf(Wf2[i]); return; }
  i -= 32768;
  if (i < 8192){ wgt[405504 + i] = f2bf(Wf3[i]); return; }
  i -= 8192;
  if (i < 12288){ wgt[413696 + i] = f2bf(Whh_n[i]); return; }
}

// ---------------- neighbor GRU + sector pooling ----------------
// 1024 blocks x 512 threads; block handles 2 batches (bi = tid>>8).
// LDS: whh[192][72] shared (27648) + per-batch 16640: hall 9216 | xs 4096 |
//      wm 2048 | dv 768 | sidv 256 | sect 256.  Total 60928 -> 2 blocks/CU.
__global__ __launch_bounds__(512, 4) void k_gru_n(
    const float* __restrict__ ttraj, const float* __restrict__ ntraj,
    const float* __restrict__ rang,  const float* __restrict__ nmask,
    const float* __restrict__ Wih_n,
    const float* __restrict__ bih_n, const float* __restrict__ bhh_n,
    const unsigned short* __restrict__ wgt,
    unsigned short* __restrict__ sf)             // [16384][96] bf16
{
  __shared__ char smem[60928];
  const int tid = threadIdx.x;
  const int bi = tid >> 8, lt = tid & 255;
  const int w = lt >> 6, u = (lt >> 4) & 3, c = lt & 15;
  const int b = blockIdx.x * 2 + bi;
  const unsigned short* whhN_b = wgt + 413696;   // [192][64]

  unsigned short* whh  = (unsigned short*)smem;                 // [192][72]
  char* pb = smem + 27648 + bi * 16640;
  unsigned short* hall = (unsigned short*)pb;                   // 4 x [16][72]
  unsigned short* hb   = hall + w * 1152;
  float* xs   = (float*)(pb + 9216);                            // [64][16]
  float* wm   = (float*)(pb + 13312);                           // [64][8]
  float* dv   = (float*)(pb + 15360);                           // [3][64]
  float* sidv = (float*)(pb + 16128);                           // [64]
  float* sect = (float*)(pb + 16384);                           // [8][8]

  // stage pre-converted bf16 Whh_n into padded LDS [192][72] (shared)
  for (int i = tid; i < 1536; i += 512){
    int r = i >> 3, cg = (i & 7) * 8;
    *(short8*)&whh[r*72 + cg] = *(const short8*)&whhN_b[r*64 + cg];
  }
  ((float4*)xs)[lt] = ((const float4*)(ntraj + (size_t)b * 1024))[lt];
  wm[lt] = 0.0f; wm[256 + lt] = 0.0f;
  __syncthreads();

  // per-lane gate constants (gate col g = gt*16 + c)
  float wr0[4],wr1[4],br_[4],wz0[4],wz1[4],bz_[4],wn0[4],wn1[4],bi_[4],bh_[4];
#pragma unroll
  for (int gt = 0; gt < 4; ++gt){
    int g = gt*16 + c;
    wr0[gt]=Wih_n[g*2];  wr1[gt]=Wih_n[g*2+1];  br_[gt]=bih_n[g]+bhh_n[g];
    int gz = 64+g;  wz0[gt]=Wih_n[gz*2]; wz1[gt]=Wih_n[gz*2+1]; bz_[gt]=bih_n[gz]+bhh_n[gz];
    int gn = 128+g; wn0[gt]=Wih_n[gn*2]; wn1[gt]=Wih_n[gn*2+1]; bi_[gt]=bih_n[gn]; bh_[gt]=bhh_n[gn];
  }
  float hcur[4][4];
#pragma unroll
  for (int gt=0; gt<4; ++gt)
#pragma unroll
    for (int q=0; q<4; ++q) hcur[gt][q] = 0.0f;

  for (int st = 0; st < 8; ++st){
    f32x4 acc[12];
    if (st > 0){
      short8 a0 = *(short8*)&hb[c*72 + u*8];
      short8 a1 = *(short8*)&hb[c*72 + 32 + u*8];
#pragma unroll
      for (int nt = 0; nt < 12; ++nt){
        short8 b0 = *(short8*)&whh[(nt*16+c)*72 + u*8];
        short8 b1 = *(short8*)&whh[(nt*16+c)*72 + 32 + u*8];
        f32x4 t = {0.f,0.f,0.f,0.f};
        t = __builtin_amdgcn_mfma_f32_16x16x32_bf16(a0, b0, t, 0,0,0);
        acc[nt] = __builtin_amdgcn_mfma_f32_16x16x32_bf16(a1, b1, t, 0,0,0);
      }
    } else {
#pragma unroll
      for (int nt = 0; nt < 12; ++nt) acc[nt] = (f32x4){0.f,0.f,0.f,0.f};
    }
    float xq0[4], xq1[4];
#pragma unroll
    for (int q=0; q<4; ++q){
      int sq = w*16 + u*4 + q;
      xq0[q] = xs[sq*16 + st*2];
      xq1[q] = xs[sq*16 + st*2 + 1];
    }
#pragma unroll
    for (int gt=0; gt<4; ++gt){
#pragma unroll
      for (int q=0; q<4; ++q){
        float x0 = xq0[q], x1 = xq1[q];
        float rp = wr0[gt]*x0 + wr1[gt]*x1 + br_[gt] + acc[gt][q];
        float zp = wz0[gt]*x0 + wz1[gt]*x1 + bz_[gt] + acc[4+gt][q];
        float r = sigf(rp), z = sigf(zp);
        float hn = acc[8+gt][q] + bh_[gt];
        float pn = wn0[gt]*x0 + wn1[gt]*x1 + bi_[gt] + r*hn;
        float n = tanhf_fast(pn);
        float hnew = n + z*(hcur[gt][q] - n);
        hcur[gt][q] = hnew;
        hb[(u*4+q)*72 + gt*16 + c] = f2bf(hnew);
      }
    }
  }
  __syncthreads();

  // ---- sector pooling (per batch bi, using lt) ----
  if (lt < 64){
    int n = lt;
    float m   = nmask[(size_t)b*64 + n];
    float ang = rang[(size_t)b*64 + n];
    float tx = ttraj[(size_t)b*16 + 14], ty = ttraj[(size_t)b*16 + 15];
    float px = xs[n*16+14], py = xs[n*16+15];
    float vx = px - xs[n*16+12], vy = py - xs[n*16+13];
    float dx = px - tx, dy = py - ty;
    float dist = __builtin_amdgcn_sqrtf(dx*dx + dy*dy);
    int sid = (int)(ang / 0.78539816339744830962f);
    sid = sid < 0 ? 0 : (sid > 7 ? 7 : sid);
    bool valid = m > 0.0f;
    float wv = valid ? __builtin_amdgcn_exp2f(dist * -0.14426950408889634f) : 0.0f;
    wm[n*8 + sid] = wv;
    dv[n]      = valid ? dist : 0.0f;
    dv[64+n]   = valid ? vx   : 0.0f;
    dv[128+n]  = valid ? vy   : 0.0f;
    sidv[n]    = valid ? (float)sid : -1.0f;
  }
  __syncthreads();
  if (lt < 8){
    int s = lt;
    float cnt=0.f, sd=0.f, sx=0.f, sy=0.f, sw=0.f;
    for (int n=0; n<64; ++n){
      if (sidv[n] == (float)s){
        cnt += 1.f; sd += dv[n]; sx += dv[64+n]; sy += dv[128+n]; sw += wm[n*8+s];
      }
    }
    float inv = (cnt > 0.f) ? __builtin_amdgcn_rcpf(cnt) : 0.f;
    sect[s*8+0] = cnt;
    sect[s*8+1] = sd * inv;
    sect[s*8+2] = sx * inv;
    sect[s*8+3] = sy * inv;
    sect[s*8+4] = __builtin_amdgcn_rcpf(sw + 1e-8f);
  }
  __syncthreads();
#pragma unroll
  for (int rep = 0; rep < 2; ++rep){
    int p = lt + rep*256;
    int s = p >> 6, h = p & 63;
    float a = 0.f;
    for (int n = 0; n < 64; ++n){
      float wmv = wm[n*8 + s];
      float nf  = bf2f(hall[(n>>4)*1152 + (n&15)*72 + h]);
      a += wmv * nf;
    }
    sf[((size_t)b*8 + s)*96 + 4 + h] = f2bf(a * sect[s*8+4]);
  }
  if (lt < 32){
    int s = lt >> 2, cc = lt & 3;
    sf[((size_t)b*8 + s)*96 + cc] = f2bf(sect[s*8+cc]);
  }
  if (lt < 224){
    int s = lt / 28, cc = 68 + lt % 28;
    sf[((size_t)b*8 + s)*96 + cc] = 0;
  }
}

// ---------------- target GRU: 128 blocks x 64 threads, 16 seqs/block ----------------
__global__ __launch_bounds__(64) void k_gru_t(
    const float* __restrict__ ttraj,
    const float* __restrict__ Wih_t, const float* __restrict__ bih_t, const float* __restrict__ bhh_t,
    const unsigned short* __restrict__ wgt,      // whhT_b [384][128] @0
    unsigned short* __restrict__ combined)       // [2048][1152] bf16
{
  __shared__ char smem[10496];
  const int tid = threadIdx.x, u = (tid >> 4) & 3, c = tid & 15;
  const unsigned short* whhT_b = wgt;
  unsigned short* hb = (unsigned short*)smem;              // [16][136]
  float* xs  = (float*)(smem + 4352);                      // [16][16]
  float* wih = (float*)(smem + 5376);                      // [384][2]
  float* bc  = (float*)(smem + 8448);                      // [384]
  float* bhn = (float*)(smem + 9984);                      // [128]

  ((float4*)xs)[tid] = ((const float4*)(ttraj + (size_t)blockIdx.x*256))[tid];
  for (int i = tid; i < 768; i += 64) wih[i] = Wih_t[i];
  for (int i = tid; i < 384; i += 64) bc[i] = bih_t[i] + ((i < 256) ? bhh_t[i] : 0.f);
  for (int i = tid; i < 128; i += 64) bhn[i] = bhh_t[256 + i];
  __syncthreads();

  for (int st = 0; st < 8; ++st){
    f32x4 acc[24];
    if (st > 0){
      short8 a0 = *(short8*)&hb[c*136 + u*8];
      short8 a1 = *(short8*)&hb[c*136 + 32 + u*8];
      short8 a2 = *(short8*)&hb[c*136 + 64 + u*8];
      short8 a3 = *(short8*)&hb[c*136 + 96 + u*8];
#pragma unroll
      for (int nt = 0; nt < 24; ++nt){
        const unsigned short* wp = whhT_b + (nt*16+c)*128 + u*8;
        f32x4 t = {0.f,0.f,0.f,0.f};
        t = __builtin_amdgcn_mfma_f32_16x16x32_bf16(a0, *(const short8*)(wp),     t, 0,0,0);
        t = __builtin_amdgcn_mfma_f32_16x16x32_bf16(a1, *(const short8*)(wp+32),  t, 0,0,0);
        t = __builtin_amdgcn_mfma_f32_16x16x32_bf16(a2, *(const short8*)(wp+64),  t, 0,0,0);
        acc[nt] = __builtin_amdgcn_mfma_f32_16x16x32_bf16(a3, *(const short8*)(wp+96), t, 0,0,0);
      }
    } else {
#pragma unroll
      for (int nt = 0; nt < 24; ++nt) acc[nt] = (f32x4){0.f,0.f,0.f,0.f};
    }
    float xq0[4], xq1[4];
#pragma unroll
    for (int q=0; q<4; ++q){
      int sq = u*4 + q;
      xq0[q] = xs[sq*16 + st*2]; xq1[q] = xs[sq*16 + st*2 + 1];
    }
#pragma unroll
    for (int gt = 0; gt < 8; ++gt){
      int g = gt*16 + c;
      float Wr0=wih[g*2],        Wr1=wih[g*2+1],        BR=bc[g];
      float Wz0=wih[(128+g)*2],  Wz1=wih[(128+g)*2+1],  BZ=bc[128+g];
      float Wn0=wih[(256+g)*2],  Wn1=wih[(256+g)*2+1],  BI=bc[256+g], BH=bhn[g];
#pragma unroll
      for (int q=0; q<4; ++q){
        float x0 = xq0[q], x1 = xq1[q];
        float rp = Wr0*x0 + Wr1*x1 + BR + acc[gt][q];
        float zp = Wz0*x0 + Wz1*x1 + BZ + acc[8+gt][q];
        float r = sigf(rp), z = sigf(zp);
        float hn = acc[16+gt][q] + BH;
        float pn = Wn0*x0 + Wn1*x1 + BI + r*hn;
        float n = tanhf_fast(pn);
        float hold = (st == 0) ? 0.f : bf2f(hb[(u*4+q)*136 + g]);
        float hnew = n + z*(hold - n);
        if (st < 7){
          hb[(u*4+q)*136 + g] = f2bf(hnew);
        } else {
          int row = blockIdx.x*16 + u*4 + q;
          combined[(size_t)row*1152 + g] = f2bf(hnew);
        }
      }
    }
  }
}

// ---------------- MLP1/MLP2 over (b,s) rows: sf -> enc part of combined ----------------
__global__ __launch_bounds__(256) void k_mlp12(
    const unsigned short* __restrict__ sf,    // [16384][96]
    const unsigned short* __restrict__ wgt,
    const float* __restrict__ b1, const float* __restrict__ b2,
    unsigned short* __restrict__ combined)
{
  __shared__ char smem[18432];
  unsigned short* hb = (unsigned short*)smem + (threadIdx.x >> 6) * 2176;  // [16][136]/wave
  float* b1s = (float*)(smem + 17408);
  float* b2s = b1s + 128;
  const unsigned short* w1b = wgt + 49152;
  const unsigned short* w2b = wgt + 61440;
  const int tid = threadIdx.x, w = tid >> 6, u = (tid >> 4) & 3, c = tid & 15;
  if (tid < 128){ b1s[tid] = b1[tid]; b2s[tid] = b2[tid]; }
  __syncthreads();
  const int rowb = blockIdx.x * 64 + w * 16;

  f32x4 acc[8];
#pragma unroll
  for (int nt=0; nt<8; ++nt) acc[nt] = (f32x4){0.f,0.f,0.f,0.f};
#pragma unroll
  for (int kc=0; kc<3; ++kc){
    short8 a = *(const short8*)&sf[(size_t)(rowb + c)*96 + kc*32 + u*8];
#pragma unroll
    for (int nt=0; nt<8; ++nt){
      short8 bb = *(const short8*)&w1b[(nt*16+c)*96 + kc*32 + u*8];
      acc[nt] = __builtin_amdgcn_mfma_f32_16x16x32_bf16(a, bb, acc[nt], 0,0,0);
    }
  }
#pragma unroll
  for (int nt=0; nt<8; ++nt){
    float bias = b1s[nt*16+c];
#pragma unroll
    for (int q=0; q<4; ++q){
      float v = acc[nt][q] + bias; v = v > 0.f ? v : 0.f;
      hb[(u*4+q)*136 + nt*16 + c] = f2bf(v);
    }
  }
  f32x4 acc2[8];
#pragma unroll
  for (int nt=0; nt<8; ++nt) acc2[nt] = (f32x4){0.f,0.f,0.f,0.f};
#pragma unroll
  for (int kc=0; kc<4; ++kc){
    short8 a = *(short8*)&hb[c*136 + kc*32 + u*8];
#pragma unroll
    for (int nt=0; nt<8; ++nt){
      short8 bb = *(const short8*)&w2b[(nt*16+c)*128 + kc*32 + u*8];
      acc2[nt] = __builtin_amdgcn_mfma_f32_16x16x32_bf16(a, bb, acc2[nt], 0,0,0);
    }
  }
#pragma unroll
  for (int nt=0; nt<8; ++nt){
    float bias = b2s[nt*16+c];
#pragma unroll
    for (int q=0; q<4; ++q){
      float v = acc2[nt][q] + bias; v = v > 0.f ? v : 0.f;
      int r = rowb + u*4 + q;
      combined[(size_t)(r >> 3)*1152 + 128 + (r & 7)*128 + nt*16 + c] = f2bf(v);
    }
  }
}

// ---------------- head: f1 -> f2 -> f3 -> LayerNorm -> out ----------------
// 128 blocks x 64 threads (1 wave), 16 rows/block.
__global__ __launch_bounds__(64) void k_head(
    const unsigned short* __restrict__ combined,
    const unsigned short* __restrict__ wgt,
    const float* __restrict__ bf1, const float* __restrict__ bf2, const float* __restrict__ bf3,
    const float* __restrict__ lng, const float* __restrict__ lnb,
    float* __restrict__ out)
{
  __shared__ char smem[15104];
  const int tid = threadIdx.x, u = (tid >> 4) & 3, c = tid & 15;
  unsigned short* f1b = (unsigned short*)smem;                 // [16][264]
  unsigned short* f2b = (unsigned short*)(smem + 8448);        // [16][136]
  float* bf1s = (float*)(smem + 12800); float* bf2s = (float*)(smem + 13824);
  float* bf3s = (float*)(smem + 14336);
  float* lngs = (float*)(smem + 14592); float* lnbs = (float*)(smem + 14848);
  const unsigned short* wf1b = wgt + 77824;
  const unsigned short* wf2b = wgt + 372736;
  const unsigned short* wf3b = wgt + 405504;
  for (int i = tid; i < 256; i += 64) bf1s[i] = bf1[i];
  for (int i = tid; i < 128; i += 64) bf2s[i] = bf2[i];
  bf3s[tid] = bf3[tid]; lngs[tid] = lng[tid]; lnbs[tid] = lnb[tid];
  __syncthreads();
  const int rowb = blockIdx.x * 16;

  f32x4 acc[16];
#pragma unroll
  for (int nt=0; nt<16; ++nt) acc[nt] = (f32x4){0.f,0.f,0.f,0.f};
  for (int kc=0; kc<36; ++kc){
    short8 a = *(const short8*)&combined[(size_t)(rowb + c)*1152 + kc*32 + u*8];
#pragma unroll
    for (int nt=0; nt<16; ++nt){
      short8 bb = *(const short8*)&wf1b[(size_t)(nt*16+c)*1152 + kc*32 + u*8];
      acc[nt] = __builtin_amdgcn_mfma_f32_16x16x32_bf16(a, bb, acc[nt], 0,0,0);
    }
  }
#pragma unroll
  for (int nt=0; nt<16; ++nt){
    float bias = bf1s[nt*16+c];
#pragma unroll
    for (int q=0; q<4; ++q){
      float v = acc[nt][q] + bias; v = v > 0.f ? v : 0.f;
      f1b[(u*4+q)*264 + nt*16 + c] = f2bf(v);
    }
  }
  __syncthreads();
  f32x4 acc2[8];
#pragma unroll
  for (int nt=0; nt<8; ++nt) acc2[nt] = (f32x4){0.f,0.f,0.f,0.f};
#pragma unroll
  for (int kc=0; kc<8; ++kc){
    short8 a = *(short8*)&f1b[c*264 + kc*32 + u*8];
#pragma unroll
    for (int nt=0; nt<8; ++nt){
      short8 bb = *(const short8*)&wf2b[(nt*16+c)*256 + kc*32 + u*8];
      acc2[nt] = __builtin_amdgcn_mfma_f32_16x16x32_bf16(a, bb, acc2[nt], 0,0,0);
    }
  }
#pragma unroll
  for (int nt=0; nt<8; ++nt){
    float bias = bf2s[nt*16+c];
#pragma unroll
    for (int q=0; q<4; ++q){
      float v = acc2[nt][q] + bias; v = v > 0.f ? v : 0.f;
      f2b[(u*4+q)*136 + nt*16 + c] = f2bf(v);
    }
  }
  __syncthreads();
  f32x4 acc3[4];
#pragma unroll
  for (int nt=0; nt<4; ++nt) acc3[nt] = (f32x4){0.f,0.f,0.f,0.f};
#pragma unroll
  for (int kc=0; kc<4; ++kc){
    short8 a = *(short8*)&f2b[c*136 + kc*32 + u*8];
#pragma unroll
    for (int nt=0; nt<4; ++nt){
      short8 bb = *(const short8*)&wf3b[(nt*16+c)*128 + kc*32 + u*8];
      acc3[nt] = __builtin_amdgcn_mfma_f32_16x16x32_bf16(a, bb, acc3[nt], 0,0,0);
    }
  }
  float v[4][4];
#pragma unroll
  for (int nt=0; nt<4; ++nt){
    float bias = bf3s[nt*16+c];
#pragma unroll
    for (int q=0; q<4; ++q){
      float t = acc3[nt][q] + bias; v[nt][q] = t > 0.f ? t : 0.f;
    }
  }
#pragma unroll
  for (int q=0; q<4; ++q){
    float p = v[0][q] + v[1][q] + v[2][q] + v[3][q];
    p += __shfl_xor(p, 1); p += __shfl_xor(p, 2); p += __shfl_xor(p, 4); p += __shfl_xor(p, 8);
    float mu = p * 0.015625f;
    float d0 = v[0][q]-mu, d1 = v[1][q]-mu, d2 = v[2][q]-mu, d3 = v[3][q]-mu;
    float p2 = d0*d0 + d1*d1 + d2*d2 + d3*d3;
    p2 += __shfl_xor(p2, 1); p2 += __shfl_xor(p2, 2); p2 += __shfl_xor(p2, 4); p2 += __shfl_xor(p2, 8);
    float rstd = __builtin_amdgcn_rsqf(p2 * 0.015625f + 1e-5f);
    int row = rowb + u*4 + q;
#pragma unroll
    for (int nt=0; nt<4; ++nt){
      int col = nt*16 + c;
      out[(size_t)row*64 + col] = (v[nt][q] - mu) * rstd * lngs[col] + lnbs[col];
    }
  }
}

extern "C" void kernel_launch(void* const* d_in, const int* in_sizes, int n_in,
                              void* d_out, int out_size, void* d_ws, size_t ws_size,
                              hipStream_t stream)
{
  const float* ttraj = (const float*)d_in[0];
  const float* ntraj = (const float*)d_in[1];
  const float* rang  = (const float*)d_in[2];
  const float* nmask = (const float*)d_in[3];
  const float* Wih_t = (const float*)d_in[4];
  const float* Whh_t = (const float*)d_in[5];
  const float* bih_t = (const float*)d_in[6];
  const float* bhh_t = (const float*)d_in[7];
  const float* Wih_n = (const float*)d_in[8];
  const float* Whh_n = (const float*)d_in[9];
  const float* bih_n = (const float*)d_in[10];
  const float* bhh_n = (const float*)d_in[11];
  const float* W1  = (const float*)d_in[12];
  const float* b1  = (const float*)d_in[13];
  const float* W2  = (const float*)d_in[14];
  const float* b2  = (const float*)d_in[15];
  const float* Wf1 = (const float*)d_in[16];
  const float* bf1 = (const float*)d_in[17];
  const float* Wf2 = (const float*)d_in[18];
  const float* bf2 = (const float*)d_in[19];
  const float* Wf3 = (const float*)d_in[20];
  const float* bf3 = (const float*)d_in[21];
  const float* lng = (const float*)d_in[22];
  const float* lnb = (const float*)d_in[23];

  char* ws = (char*)d_ws;
  unsigned short* combined = (unsigned short*)ws;                  // [2048][1152] bf16
  unsigned short* sf       = (unsigned short*)(ws + 5242880);      // [16384][96] bf16
  unsigned short* wgt      = (unsigned short*)(ws + 8388608);      // bf16 weights

  hipLaunchKernelGGL(k_prep, dim3(1664), dim3(256), 0, stream,
                     Whh_t, W1, W2, Wf1, Wf2, Wf3, Whh_n, wgt);
  hipLaunchKernelGGL(k_gru_t, dim3(128), dim3(64), 0, stream,
                     ttraj, Wih_t, bih_t, bhh_t, wgt, combined);
  hipLaunchKernelGGL(k_gru_n, dim3(1024), dim3(512), 0, stream,
                     ttraj, ntraj, rang, nmask, Wih_n, bih_n, bhh_n, wgt, sf);
  hipLaunchKernelGGL(k_mlp12, dim3(256), dim3(256), 0, stream, sf, wgt, b1, b2, combined);
  hipLaunchKernelGGL(k_head, dim3(128), dim3(64), 0, stream,
                     combined, wgt, bf1, bf2, bf3, lng, lnb, (float*)d_out);
}

// Round 4
// 150.546 us; speedup vs baseline: 1.9800x; 1.9800x over previous
//
#include <hip/hip_runtime.h>

typedef __attribute__((ext_vector_type(8))) short short8;
typedef __attribute__((ext_vector_type(4))) float f32x4;

__device__ __forceinline__ unsigned short f2bf(float f){
  unsigned u = __float_as_uint(f);
  return (unsigned short)((u + 0x7fffu + ((u >> 16) & 1u)) >> 16);
}
__device__ __forceinline__ float bf2f(unsigned short b){
  return __uint_as_float(((unsigned)b) << 16);
}
__device__ __forceinline__ float sigf(float v){
  return __builtin_amdgcn_rcpf(1.0f + __builtin_amdgcn_exp2f(v * -1.44269504088896341f));
}
__device__ __forceinline__ float tanhf_fast(float v){
  float e = __builtin_amdgcn_exp2f(v * 2.88539008177792681f);
  return (e - 1.0f) * __builtin_amdgcn_rcpf(e + 1.0f);
}

// ---------------- weight conversion: fp32 -> bf16 in ws ----------------
// wgt layout (u16 elems):
//   whhT_b [384*128]  @0
//   W1b    [128*96]   @49152   (96 = 68 padded, zeros)
//   W2b    [128*128]  @61440
//   Wf1b   [256*1152] @77824
//   Wf2b   [128*256]  @372736
//   Wf3b   [64*128]   @405504
//   whhN_b [192*64]   @413696
__global__ __launch_bounds__(256) void k_prep(
    const float* __restrict__ Whh_t, const float* __restrict__ W1,
    const float* __restrict__ W2,    const float* __restrict__ Wf1,
    const float* __restrict__ Wf2,   const float* __restrict__ Wf3,
    const float* __restrict__ Whh_n,
    unsigned short* __restrict__ wgt)
{
  int i = blockIdx.x * 256 + threadIdx.x;
  if (i < 49152){ wgt[i] = f2bf(Whh_t[i]); return; }
  i -= 49152;
  if (i < 12288){ int r = i / 96, c = i % 96;
    wgt[49152 + i] = (c < 68) ? f2bf(W1[r*68 + c]) : (unsigned short)0; return; }
  i -= 12288;
  if (i < 16384){ wgt[61440 + i] = f2bf(W2[i]); return; }
  i -= 16384;
  if (i < 294912){ wgt[77824 + i] = f2bf(Wf1[i]); return; }
  i -= 294912;
  if (i < 32768){ wgt[372736 + i] = f2bf(Wf2[i]); return; }
  i -= 32768;
  if (i < 8192){ wgt[405504 + i] = f2bf(Wf3[i]); return; }
  i -= 8192;
  if (i < 12288){ wgt[413696 + i] = f2bf(Whh_n[i]); return; }
}

// ---------------- neighbor GRU + sector pooling ----------------
// 1024 blocks x 512 threads; block handles 2 batches (bi = tid>>8).
__global__ __launch_bounds__(512, 4) void k_gru_n(
    const float* __restrict__ ttraj, const float* __restrict__ ntraj,
    const float* __restrict__ rang,  const float* __restrict__ nmask,
    const float* __restrict__ Wih_n,
    const float* __restrict__ bih_n, const float* __restrict__ bhh_n,
    const unsigned short* __restrict__ wgt,
    unsigned short* __restrict__ sf)             // [16384][96] bf16
{
  __shared__ char smem[60928];
  const int tid = threadIdx.x;
  const int bi = tid >> 8, lt = tid & 255;
  const int w = lt >> 6, u = (lt >> 4) & 3, c = lt & 15;
  const int b = blockIdx.x * 2 + bi;
  const unsigned short* whhN_b = wgt + 413696;   // [192][64]

  unsigned short* whh  = (unsigned short*)smem;                 // [192][72]
  char* pb = smem + 27648 + bi * 16640;
  unsigned short* hall = (unsigned short*)pb;                   // 4 x [16][72]
  unsigned short* hb   = hall + w * 1152;
  float* xs   = (float*)(pb + 9216);                            // [64][16]
  float* wm   = (float*)(pb + 13312);                           // [64][8]
  float* dv   = (float*)(pb + 15360);                           // [3][64]
  float* sidv = (float*)(pb + 16128);                           // [64]
  float* sect = (float*)(pb + 16384);                           // [8][8]

  for (int i = tid; i < 1536; i += 512){
    int r = i >> 3, cg = (i & 7) * 8;
    *(short8*)&whh[r*72 + cg] = *(const short8*)&whhN_b[r*64 + cg];
  }
  ((float4*)xs)[lt] = ((const float4*)(ntraj + (size_t)b * 1024))[lt];
  wm[lt] = 0.0f; wm[256 + lt] = 0.0f;
  __syncthreads();

  float wr0[4],wr1[4],br_[4],wz0[4],wz1[4],bz_[4],wn0[4],wn1[4],bi_[4],bh_[4];
#pragma unroll
  for (int gt = 0; gt < 4; ++gt){
    int g = gt*16 + c;
    wr0[gt]=Wih_n[g*2];  wr1[gt]=Wih_n[g*2+1];  br_[gt]=bih_n[g]+bhh_n[g];
    int gz = 64+g;  wz0[gt]=Wih_n[gz*2]; wz1[gt]=Wih_n[gz*2+1]; bz_[gt]=bih_n[gz]+bhh_n[gz];
    int gn = 128+g; wn0[gt]=Wih_n[gn*2]; wn1[gt]=Wih_n[gn*2+1]; bi_[gt]=bih_n[gn]; bh_[gt]=bhh_n[gn];
  }
  float hcur[4][4];
#pragma unroll
  for (int gt=0; gt<4; ++gt)
#pragma unroll
    for (int q=0; q<4; ++q) hcur[gt][q] = 0.0f;

  for (int st = 0; st < 8; ++st){
    f32x4 acc[12];
    if (st > 0){
      short8 a0 = *(short8*)&hb[c*72 + u*8];
      short8 a1 = *(short8*)&hb[c*72 + 32 + u*8];
#pragma unroll
      for (int nt = 0; nt < 12; ++nt){
        short8 b0 = *(short8*)&whh[(nt*16+c)*72 + u*8];
        short8 b1 = *(short8*)&whh[(nt*16+c)*72 + 32 + u*8];
        f32x4 t = {0.f,0.f,0.f,0.f};
        t = __builtin_amdgcn_mfma_f32_16x16x32_bf16(a0, b0, t, 0,0,0);
        acc[nt] = __builtin_amdgcn_mfma_f32_16x16x32_bf16(a1, b1, t, 0,0,0);
      }
    } else {
#pragma unroll
      for (int nt = 0; nt < 12; ++nt) acc[nt] = (f32x4){0.f,0.f,0.f,0.f};
    }
    float xq0[4], xq1[4];
#pragma unroll
    for (int q=0; q<4; ++q){
      int sq = w*16 + u*4 + q;
      xq0[q] = xs[sq*16 + st*2];
      xq1[q] = xs[sq*16 + st*2 + 1];
    }
#pragma unroll
    for (int gt=0; gt<4; ++gt){
#pragma unroll
      for (int q=0; q<4; ++q){
        float x0 = xq0[q], x1 = xq1[q];
        float rp = wr0[gt]*x0 + wr1[gt]*x1 + br_[gt] + acc[gt][q];
        float zp = wz0[gt]*x0 + wz1[gt]*x1 + bz_[gt] + acc[4+gt][q];
        float r = sigf(rp), z = sigf(zp);
        float hn = acc[8+gt][q] + bh_[gt];
        float pn = wn0[gt]*x0 + wn1[gt]*x1 + bi_[gt] + r*hn;
        float n = tanhf_fast(pn);
        float hnew = n + z*(hcur[gt][q] - n);
        hcur[gt][q] = hnew;
        hb[(u*4+q)*72 + gt*16 + c] = f2bf(hnew);
      }
    }
  }
  __syncthreads();

  if (lt < 64){
    int n = lt;
    float m   = nmask[(size_t)b*64 + n];
    float ang = rang[(size_t)b*64 + n];
    float tx = ttraj[(size_t)b*16 + 14], ty = ttraj[(size_t)b*16 + 15];
    float px = xs[n*16+14], py = xs[n*16+15];
    float vx = px - xs[n*16+12], vy = py - xs[n*16+13];
    float dx = px - tx, dy = py - ty;
    float dist = __builtin_amdgcn_sqrtf(dx*dx + dy*dy);
    int sid = (int)(ang / 0.78539816339744830962f);
    sid = sid < 0 ? 0 : (sid > 7 ? 7 : sid);
    bool valid = m > 0.0f;
    float wv = valid ? __builtin_amdgcn_exp2f(dist * -0.14426950408889634f) : 0.0f;
    wm[n*8 + sid] = wv;
    dv[n]      = valid ? dist : 0.0f;
    dv[64+n]   = valid ? vx   : 0.0f;
    dv[128+n]  = valid ? vy   : 0.0f;
    sidv[n]    = valid ? (float)sid : -1.0f;
  }
  __syncthreads();
  if (lt < 8){
    int s = lt;
    float cnt=0.f, sd=0.f, sx=0.f, sy=0.f, sw=0.f;
    for (int n=0; n<64; ++n){
      if (sidv[n] == (float)s){
        cnt += 1.f; sd += dv[n]; sx += dv[64+n]; sy += dv[128+n]; sw += wm[n*8+s];
      }
    }
    float inv = (cnt > 0.f) ? __builtin_amdgcn_rcpf(cnt) : 0.f;
    sect[s*8+0] = cnt;
    sect[s*8+1] = sd * inv;
    sect[s*8+2] = sx * inv;
    sect[s*8+3] = sy * inv;
    sect[s*8+4] = __builtin_amdgcn_rcpf(sw + 1e-8f);
  }
  __syncthreads();
#pragma unroll
  for (int rep = 0; rep < 2; ++rep){
    int p = lt + rep*256;
    int s = p >> 6, h = p & 63;
    float a = 0.f;
    for (int n = 0; n < 64; ++n){
      float wmv = wm[n*8 + s];
      float nf  = bf2f(hall[(n>>4)*1152 + (n&15)*72 + h]);
      a += wmv * nf;
    }
    sf[((size_t)b*8 + s)*96 + 4 + h] = f2bf(a * sect[s*8+4]);
  }
  if (lt < 32){
    int s = lt >> 2, cc = lt & 3;
    sf[((size_t)b*8 + s)*96 + cc] = f2bf(sect[s*8+cc]);
  }
  if (lt < 224){
    int s = lt / 28, cc = 68 + lt % 28;
    sf[((size_t)b*8 + s)*96 + cc] = 0;
  }
}

// ---------------- target GRU v2: 128 blocks x 256 thr (4 waves) ----------------
// Block handles 16 seqs. Wave w owns hidden slice [w*32, w*32+32):
// 6 gate-col tiles (r: 2w,2w+1 | z: 8+2w,9+2w | n: 16+2w,17+2w), B-frags
// register-resident (loaded from L2 once). h double-buffered in LDS.
__global__ __launch_bounds__(256) void k_gru_t(
    const float* __restrict__ ttraj,
    const float* __restrict__ Wih_t, const float* __restrict__ bih_t, const float* __restrict__ bhh_t,
    const unsigned short* __restrict__ wgt,      // whhT_b [384][128] @0
    unsigned short* __restrict__ combined)       // [2048][1152] bf16
{
  __shared__ char smem[9728];
  const int tid = threadIdx.x, w = tid >> 6, u = (tid >> 4) & 3, c = tid & 15;
  unsigned short* hb0 = (unsigned short*)smem;             // [16][136]
  unsigned short* hb1 = (unsigned short*)(smem + 4352);    // [16][136]
  float* xs = (float*)(smem + 8704);                       // [16][16]

  xs[tid] = ttraj[(size_t)blockIdx.x*256 + tid];

  // global nt indices for this wave's 6 tiles
  int ntg[6];
  ntg[0] = 2*w; ntg[1] = 2*w+1;
  ntg[2] = 8+2*w; ntg[3] = 9+2*w;
  ntg[4] = 16+2*w; ntg[5] = 17+2*w;

  // register-resident B fragments: 6 tiles x 4 k-chunks
  short8 Bf[6][4];
#pragma unroll
  for (int lt2 = 0; lt2 < 6; ++lt2){
    const unsigned short* wp = wgt + (ntg[lt2]*16 + c)*128 + u*8;
#pragma unroll
    for (int kk = 0; kk < 4; ++kk)
      Bf[lt2][kk] = *(const short8*)(wp + kk*32);
  }

  // per-lane gate constants for gt in {0,1}: col g = w*32 + gt*16 + c
  float Wr0[2],Wr1[2],BR[2],Wz0[2],Wz1[2],BZ[2],Wn0[2],Wn1[2],BI[2],BH[2];
#pragma unroll
  for (int gt = 0; gt < 2; ++gt){
    int g = w*32 + gt*16 + c;
    Wr0[gt]=Wih_t[g*2];        Wr1[gt]=Wih_t[g*2+1];        BR[gt]=bih_t[g]+bhh_t[g];
    Wz0[gt]=Wih_t[(128+g)*2];  Wz1[gt]=Wih_t[(128+g)*2+1];  BZ[gt]=bih_t[128+g]+bhh_t[128+g];
    Wn0[gt]=Wih_t[(256+g)*2];  Wn1[gt]=Wih_t[(256+g)*2+1];  BI[gt]=bih_t[256+g]; BH[gt]=bhh_t[256+g];
  }
  float hcur[2][4];
#pragma unroll
  for (int gt=0; gt<2; ++gt)
#pragma unroll
    for (int q=0; q<4; ++q) hcur[gt][q] = 0.0f;
  __syncthreads();

  for (int st = 0; st < 8; ++st){
    unsigned short* rbuf = (st & 1) ? hb0 : hb1;   // written at st-1
    unsigned short* wbuf = (st & 1) ? hb1 : hb0;
    f32x4 acc[6];
    if (st > 0){
      short8 a0 = *(short8*)&rbuf[c*136 + u*8];
      short8 a1 = *(short8*)&rbuf[c*136 + 32 + u*8];
      short8 a2 = *(short8*)&rbuf[c*136 + 64 + u*8];
      short8 a3 = *(short8*)&rbuf[c*136 + 96 + u*8];
#pragma unroll
      for (int lt2 = 0; lt2 < 6; ++lt2){
        f32x4 t = {0.f,0.f,0.f,0.f};
        t = __builtin_amdgcn_mfma_f32_16x16x32_bf16(a0, Bf[lt2][0], t, 0,0,0);
        t = __builtin_amdgcn_mfma_f32_16x16x32_bf16(a1, Bf[lt2][1], t, 0,0,0);
        t = __builtin_amdgcn_mfma_f32_16x16x32_bf16(a2, Bf[lt2][2], t, 0,0,0);
        acc[lt2] = __builtin_amdgcn_mfma_f32_16x16x32_bf16(a3, Bf[lt2][3], t, 0,0,0);
      }
    } else {
#pragma unroll
      for (int lt2 = 0; lt2 < 6; ++lt2) acc[lt2] = (f32x4){0.f,0.f,0.f,0.f};
    }
#pragma unroll
    for (int gt = 0; gt < 2; ++gt){
#pragma unroll
      for (int q = 0; q < 4; ++q){
        int sq = u*4 + q;
        float x0 = xs[sq*16 + st*2], x1 = xs[sq*16 + st*2 + 1];
        float rp = Wr0[gt]*x0 + Wr1[gt]*x1 + BR[gt] + acc[gt][q];
        float zp = Wz0[gt]*x0 + Wz1[gt]*x1 + BZ[gt] + acc[2+gt][q];
        float r = sigf(rp), z = sigf(zp);
        float hn = acc[4+gt][q] + BH[gt];
        float pn = Wn0[gt]*x0 + Wn1[gt]*x1 + BI[gt] + r*hn;
        float n = tanhf_fast(pn);
        float hnew = n + z*(hcur[gt][q] - n);
        hcur[gt][q] = hnew;
        if (st < 7){
          wbuf[sq*136 + w*32 + gt*16 + c] = f2bf(hnew);
        } else {
          int row = blockIdx.x*16 + sq;
          combined[(size_t)row*1152 + w*32 + gt*16 + c] = f2bf(hnew);
        }
      }
    }
    if (st < 7) __syncthreads();
  }
}

// ---------------- MLP1/MLP2 over (b,s) rows: sf -> enc part of combined ----------------
__global__ __launch_bounds__(256) void k_mlp12(
    const unsigned short* __restrict__ sf,    // [16384][96]
    const unsigned short* __restrict__ wgt,
    const float* __restrict__ b1, const float* __restrict__ b2,
    unsigned short* __restrict__ combined)
{
  __shared__ char smem[18432];
  unsigned short* hb = (unsigned short*)smem + (threadIdx.x >> 6) * 2176;  // [16][136]/wave
  float* b1s = (float*)(smem + 17408);
  float* b2s = b1s + 128;
  const unsigned short* w1b = wgt + 49152;
  const unsigned short* w2b = wgt + 61440;
  const int tid = threadIdx.x, w = tid >> 6, u = (tid >> 4) & 3, c = tid & 15;
  if (tid < 128){ b1s[tid] = b1[tid]; b2s[tid] = b2[tid]; }
  __syncthreads();
  const int rowb = blockIdx.x * 64 + w * 16;

  f32x4 acc[8];
#pragma unroll
  for (int nt=0; nt<8; ++nt) acc[nt] = (f32x4){0.f,0.f,0.f,0.f};
#pragma unroll
  for (int kc=0; kc<3; ++kc){
    short8 a = *(const short8*)&sf[(size_t)(rowb + c)*96 + kc*32 + u*8];
#pragma unroll
    for (int nt=0; nt<8; ++nt){
      short8 bb = *(const short8*)&w1b[(nt*16+c)*96 + kc*32 + u*8];
      acc[nt] = __builtin_amdgcn_mfma_f32_16x16x32_bf16(a, bb, acc[nt], 0,0,0);
    }
  }
#pragma unroll
  for (int nt=0; nt<8; ++nt){
    float bias = b1s[nt*16+c];
#pragma unroll
    for (int q=0; q<4; ++q){
      float v = acc[nt][q] + bias; v = v > 0.f ? v : 0.f;
      hb[(u*4+q)*136 + nt*16 + c] = f2bf(v);
    }
  }
  f32x4 acc2[8];
#pragma unroll
  for (int nt=0; nt<8; ++nt) acc2[nt] = (f32x4){0.f,0.f,0.f,0.f};
#pragma unroll
  for (int kc=0; kc<4; ++kc){
    short8 a = *(short8*)&hb[c*136 + kc*32 + u*8];
#pragma unroll
    for (int nt=0; nt<8; ++nt){
      short8 bb = *(const short8*)&w2b[(nt*16+c)*128 + kc*32 + u*8];
      acc2[nt] = __builtin_amdgcn_mfma_f32_16x16x32_bf16(a, bb, acc2[nt], 0,0,0);
    }
  }
#pragma unroll
  for (int nt=0; nt<8; ++nt){
    float bias = b2s[nt*16+c];
#pragma unroll
    for (int q=0; q<4; ++q){
      float v = acc2[nt][q] + bias; v = v > 0.f ? v : 0.f;
      int r = rowb + u*4 + q;
      combined[(size_t)(r >> 3)*1152 + 128 + (r & 7)*128 + nt*16 + c] = f2bf(v);
    }
  }
}

// ---------------- head v2: 128 blocks x 256 thr (4 waves) ----------------
// f1: wave w computes nt = w*4..w*4+3 ; f2: nt = w*2,w*2+1 ; f3+LN: all waves
// redundant, wave 0 stores.
__global__ __launch_bounds__(256) void k_head(
    const unsigned short* __restrict__ combined,
    const unsigned short* __restrict__ wgt,
    const float* __restrict__ bf1, const float* __restrict__ bf2, const float* __restrict__ bf3,
    const float* __restrict__ lng, const float* __restrict__ lnb,
    float* __restrict__ out)
{
  __shared__ char smem[15104];
  const int tid = threadIdx.x, w = tid >> 6, u = (tid >> 4) & 3, c = tid & 15;
  unsigned short* f1b = (unsigned short*)smem;                 // [16][264]
  unsigned short* f2b = (unsigned short*)(smem + 8448);        // [16][136]
  float* bf1s = (float*)(smem + 12800); float* bf2s = (float*)(smem + 13824);
  float* bf3s = (float*)(smem + 14336);
  float* lngs = (float*)(smem + 14592); float* lnbs = (float*)(smem + 14848);
  const unsigned short* wf1b = wgt + 77824;
  const unsigned short* wf2b = wgt + 372736;
  const unsigned short* wf3b = wgt + 405504;
  bf1s[tid] = bf1[tid];
  if (tid < 128) bf2s[tid] = bf2[tid];
  if (tid < 64){ bf3s[tid] = bf3[tid]; lngs[tid] = lng[tid]; lnbs[tid] = lnb[tid]; }
  __syncthreads();
  const int rowb = blockIdx.x * 16;

  // f1: 4 nt per wave
  f32x4 acc[4];
#pragma unroll
  for (int i=0; i<4; ++i) acc[i] = (f32x4){0.f,0.f,0.f,0.f};
#pragma unroll 4
  for (int kc=0; kc<36; ++kc){
    short8 a = *(const short8*)&combined[(size_t)(rowb + c)*1152 + kc*32 + u*8];
#pragma unroll
    for (int i=0; i<4; ++i){
      int nt = w*4 + i;
      short8 bb = *(const short8*)&wf1b[(size_t)(nt*16+c)*1152 + kc*32 + u*8];
      acc[i] = __builtin_amdgcn_mfma_f32_16x16x32_bf16(a, bb, acc[i], 0,0,0);
    }
  }
#pragma unroll
  for (int i=0; i<4; ++i){
    int nt = w*4 + i;
    float bias = bf1s[nt*16+c];
#pragma unroll
    for (int q=0; q<4; ++q){
      float v = acc[i][q] + bias; v = v > 0.f ? v : 0.f;
      f1b[(u*4+q)*264 + nt*16 + c] = f2bf(v);
    }
  }
  __syncthreads();

  // f2: 2 nt per wave
  f32x4 acc2[2];
#pragma unroll
  for (int i=0; i<2; ++i) acc2[i] = (f32x4){0.f,0.f,0.f,0.f};
#pragma unroll
  for (int kc=0; kc<8; ++kc){
    short8 a = *(short8*)&f1b[c*264 + kc*32 + u*8];
#pragma unroll
    for (int i=0; i<2; ++i){
      int nt = w*2 + i;
      short8 bb = *(const short8*)&wf2b[(nt*16+c)*256 + kc*32 + u*8];
      acc2[i] = __builtin_amdgcn_mfma_f32_16x16x32_bf16(a, bb, acc2[i], 0,0,0);
    }
  }
#pragma unroll
  for (int i=0; i<2; ++i){
    int nt = w*2 + i;
    float bias = bf2s[nt*16+c];
#pragma unroll
    for (int q=0; q<4; ++q){
      float v = acc2[i][q] + bias; v = v > 0.f ? v : 0.f;
      f2b[(u*4+q)*136 + nt*16 + c] = f2bf(v);
    }
  }
  __syncthreads();

  // f3 + LN: all waves compute (redundant), wave 0 stores
  f32x4 acc3[4];
#pragma unroll
  for (int nt=0; nt<4; ++nt) acc3[nt] = (f32x4){0.f,0.f,0.f,0.f};
#pragma unroll
  for (int kc=0; kc<4; ++kc){
    short8 a = *(short8*)&f2b[c*136 + kc*32 + u*8];
#pragma unroll
    for (int nt=0; nt<4; ++nt){
      short8 bb = *(const short8*)&wf3b[(nt*16+c)*128 + kc*32 + u*8];
      acc3[nt] = __builtin_amdgcn_mfma_f32_16x16x32_bf16(a, bb, acc3[nt], 0,0,0);
    }
  }
  if (w == 0){
    float v[4][4];
#pragma unroll
    for (int nt=0; nt<4; ++nt){
      float bias = bf3s[nt*16+c];
#pragma unroll
      for (int q=0; q<4; ++q){
        float t = acc3[nt][q] + bias; v[nt][q] = t > 0.f ? t : 0.f;
      }
    }
#pragma unroll
    for (int q=0; q<4; ++q){
      float p = v[0][q] + v[1][q] + v[2][q] + v[3][q];
      p += __shfl_xor(p, 1); p += __shfl_xor(p, 2); p += __shfl_xor(p, 4); p += __shfl_xor(p, 8);
      float mu = p * 0.015625f;
      float d0 = v[0][q]-mu, d1 = v[1][q]-mu, d2 = v[2][q]-mu, d3 = v[3][q]-mu;
      float p2 = d0*d0 + d1*d1 + d2*d2 + d3*d3;
      p2 += __shfl_xor(p2, 1); p2 += __shfl_xor(p2, 2); p2 += __shfl_xor(p2, 4); p2 += __shfl_xor(p2, 8);
      float rstd = __builtin_amdgcn_rsqf(p2 * 0.015625f + 1e-5f);
      int row = rowb + u*4 + q;
#pragma unroll
      for (int nt=0; nt<4; ++nt){
        int col = nt*16 + c;
        out[(size_t)row*64 + col] = (v[nt][q] - mu) * rstd * lngs[col] + lnbs[col];
      }
    }
  }
}

extern "C" void kernel_launch(void* const* d_in, const int* in_sizes, int n_in,
                              void* d_out, int out_size, void* d_ws, size_t ws_size,
                              hipStream_t stream)
{
  const float* ttraj = (const float*)d_in[0];
  const float* ntraj = (const float*)d_in[1];
  const float* rang  = (const float*)d_in[2];
  const float* nmask = (const float*)d_in[3];
  const float* Wih_t = (const float*)d_in[4];
  const float* Whh_t = (const float*)d_in[5];
  const float* bih_t = (const float*)d_in[6];
  const float* bhh_t = (const float*)d_in[7];
  const float* Wih_n = (const float*)d_in[8];
  const float* Whh_n = (const float*)d_in[9];
  const float* bih_n = (const float*)d_in[10];
  const float* bhh_n = (const float*)d_in[11];
  const float* W1  = (const float*)d_in[12];
  const float* b1  = (const float*)d_in[13];
  const float* W2  = (const float*)d_in[14];
  const float* b2  = (const float*)d_in[15];
  const float* Wf1 = (const float*)d_in[16];
  const float* bf1 = (const float*)d_in[17];
  const float* Wf2 = (const float*)d_in[18];
  const float* bf2 = (const float*)d_in[19];
  const float* Wf3 = (const float*)d_in[20];
  const float* bf3 = (const float*)d_in[21];
  const float* lng = (const float*)d_in[22];
  const float* lnb = (const float*)d_in[23];

  char* ws = (char*)d_ws;
  unsigned short* combined = (unsigned short*)ws;                  // [2048][1152] bf16
  unsigned short* sf       = (unsigned short*)(ws + 5242880);      // [16384][96] bf16
  unsigned short* wgt      = (unsigned short*)(ws + 8388608);      // bf16 weights

  hipLaunchKernelGGL(k_prep, dim3(1664), dim3(256), 0, stream,
                     Whh_t, W1, W2, Wf1, Wf2, Wf3, Whh_n, wgt);
  hipLaunchKernelGGL(k_gru_n, dim3(1024), dim3(512), 0, stream,
                     ttraj, ntraj, rang, nmask, Wih_n, bih_n, bhh_n, wgt, sf);
  hipLaunchKernelGGL(k_gru_t, dim3(128), dim3(256), 0, stream,
                     ttraj, Wih_t, bih_t, bhh_t, wgt, combined);
  hipLaunchKernelGGL(k_mlp12, dim3(256), dim3(256), 0, stream, sf, wgt, b1, b2, combined);
  hipLaunchKernelGGL(k_head, dim3(128), dim3(256), 0, stream,
                     combined, wgt, bf1, bf2, bf3, lng, lnb, (float*)d_out);
}

// Round 5
// 136.568 us; speedup vs baseline: 2.1827x; 1.1024x over previous
//
#include <hip/hip_runtime.h>

typedef __attribute__((ext_vector_type(8))) short short8;
typedef __attribute__((ext_vector_type(4))) float f32x4;

#define SGC (-1.44269504088896341f)   /* -log2(e): sigmoid prescale */
#define THC ( 2.88539008177792681f)   /* 2*log2(e): tanh prescale   */

__device__ __forceinline__ unsigned short f2bf(float f){
  unsigned u = __float_as_uint(f);
  return (unsigned short)((u + 0x7fffu + ((u >> 16) & 1u)) >> 16);
}
__device__ __forceinline__ float bf2f(unsigned short b){
  return __uint_as_float(((unsigned)b) << 16);
}
// single f32 -> bf16 (RNE) in one VALU op; low 16 bits of result are valid
__device__ __forceinline__ unsigned f2bf_cvt(float f){
  unsigned r;
  asm("v_cvt_pk_bf16_f32 %0, %1, %1" : "=v"(r) : "v"(f));
  return r;
}

// ---------------- weight conversion: fp32 -> bf16 in ws ----------------
// wgt layout (u16 elems):
//   whhT_b [384*128]  @0        (PRESCALED: rows<256 *SGC, rows>=256 *THC)
//   W1b    [128*96]   @49152    (96 = 68 padded, zeros)
//   W2b    [128*128]  @61440
//   Wf1b   [256*1152] @77824
//   Wf2b   [128*256]  @372736
//   Wf3b   [64*128]   @405504
//   whhN_b [192*64]   @413696   (PRESCALED: rows<128 *SGC, rows>=128 *THC)
__global__ __launch_bounds__(256) void k_prep(
    const float* __restrict__ Whh_t, const float* __restrict__ W1,
    const float* __restrict__ W2,    const float* __restrict__ Wf1,
    const float* __restrict__ Wf2,   const float* __restrict__ Wf3,
    const float* __restrict__ Whh_n,
    unsigned short* __restrict__ wgt)
{
  int i = blockIdx.x * 256 + threadIdx.x;
  if (i < 49152){
    int g = i >> 7;
    float s = (g < 256) ? SGC : THC;
    wgt[i] = f2bf(Whh_t[i] * s); return;
  }
  i -= 49152;
  if (i < 12288){ int r = i / 96, c = i % 96;
    wgt[49152 + i] = (c < 68) ? f2bf(W1[r*68 + c]) : (unsigned short)0; return; }
  i -= 12288;
  if (i < 16384){ wgt[61440 + i] = f2bf(W2[i]); return; }
  i -= 16384;
  if (i < 294912){ wgt[77824 + i] = f2bf(Wf1[i]); return; }
  i -= 294912;
  if (i < 32768){ wgt[372736 + i] = f2bf(Wf2[i]); return; }
  i -= 32768;
  if (i < 8192){ wgt[405504 + i] = f2bf(Wf3[i]); return; }
  i -= 8192;
  if (i < 12288){
    int g = i >> 6;
    float s = (g < 128) ? SGC : THC;
    wgt[413696 + i] = f2bf(Whh_n[i] * s); return;
  }
}

// ---------------- neighbor GRU + sector pooling ----------------
// 1024 blocks x 512 threads; block handles 2 batches (bi = tid>>8).
// Restructured: per gate-tile MFMA -> immediate gate math (12 live acc VGPRs).
__global__ __launch_bounds__(512, 4) void k_gru_n(
    const float* __restrict__ ttraj, const float* __restrict__ ntraj,
    const float* __restrict__ rang,  const float* __restrict__ nmask,
    const float* __restrict__ Wih_n,
    const float* __restrict__ bih_n, const float* __restrict__ bhh_n,
    const unsigned short* __restrict__ wgt,
    unsigned short* __restrict__ sf)             // [16384][96] bf16
{
  __shared__ char smem[62976];
  const int tid = threadIdx.x;
  const int bi = tid >> 8, lt = tid & 255;
  const int w = lt >> 6, u = (lt >> 4) & 3, c = lt & 15;
  const int b = blockIdx.x * 2 + bi;
  const unsigned short* whhN_b = wgt + 413696;   // [192][64] prescaled

  unsigned short* whh  = (unsigned short*)smem;                 // [192][72]
  char* pb = smem + 27648 + bi * 17664;
  unsigned short* hall = (unsigned short*)pb;                   // 4 x [16][72]
  unsigned short* hb   = hall + w * 1152;
  float* xs   = (float*)(pb + 9216);                            // [64][20]
  float* wm   = (float*)(pb + 14336);                           // [64][8]
  float* dv   = (float*)(pb + 16384);                           // [3][64]
  float* sidv = (float*)(pb + 17152);                           // [64]
  float* sect = (float*)(pb + 17408);                           // [8][8]

  for (int i = tid; i < 1536; i += 512){
    int r = i >> 3, cg = (i & 7) * 8;
    *(short8*)&whh[r*72 + cg] = *(const short8*)&whhN_b[r*64 + cg];
  }
  {
    int row = lt >> 2, part = lt & 3;
    *(float4*)&xs[row*20 + part*4] = ((const float4*)(ntraj + (size_t)b * 1024))[lt];
  }
  wm[lt] = 0.0f; wm[256 + lt] = 0.0f;
  __syncthreads();

  // per-lane gate constants, prescaled (gate col g = gt*16 + c)
  float wr0[4],wr1[4],br_[4],wz0[4],wz1[4],bz_[4],wn0[4],wn1[4],bi_[4],bh_[4];
#pragma unroll
  for (int gt = 0; gt < 4; ++gt){
    int g = gt*16 + c;
    wr0[gt]=Wih_n[g*2]*SGC;  wr1[gt]=Wih_n[g*2+1]*SGC;  br_[gt]=(bih_n[g]+bhh_n[g])*SGC;
    int gz = 64+g;  wz0[gt]=Wih_n[gz*2]*SGC; wz1[gt]=Wih_n[gz*2+1]*SGC; bz_[gt]=(bih_n[gz]+bhh_n[gz])*SGC;
    int gn = 128+g; wn0[gt]=Wih_n[gn*2]*THC; wn1[gt]=Wih_n[gn*2+1]*THC; bi_[gt]=bih_n[gn]*THC; bh_[gt]=bhh_n[gn]*THC;
  }
  float hcur[4][4];
#pragma unroll
  for (int gt=0; gt<4; ++gt)
#pragma unroll
    for (int q=0; q<4; ++q) hcur[gt][q] = 0.0f;

  float xq0[4], xq1[4];
  auto gates = [&](int gt, const f32x4& aR, const f32x4& aZ, const f32x4& aN){
#pragma unroll
    for (int q = 0; q < 4; ++q){
      float x0 = xq0[q], x1 = xq1[q];
      float rp = __builtin_fmaf(wr0[gt], x0, __builtin_fmaf(wr1[gt], x1, aR[q] + br_[gt]));
      float zp = __builtin_fmaf(wz0[gt], x0, __builtin_fmaf(wz1[gt], x1, aZ[q] + bz_[gt]));
      float r = __builtin_amdgcn_rcpf(1.0f + __builtin_amdgcn_exp2f(rp));
      float z = __builtin_amdgcn_rcpf(1.0f + __builtin_amdgcn_exp2f(zp));
      float hnv = aN[q] + bh_[gt];
      float pn = __builtin_fmaf(wn0[gt], x0, __builtin_fmaf(wn1[gt], x1, __builtin_fmaf(r, hnv, bi_[gt])));
      float E = __builtin_amdgcn_exp2f(pn);
      float n = __builtin_fmaf(-2.0f, __builtin_amdgcn_rcpf(E + 1.0f), 1.0f);
      float hnew = __builtin_fmaf(z, hcur[gt][q] - n, n);
      hcur[gt][q] = hnew;
      hb[(u*4+q)*72 + gt*16 + c] = (unsigned short)f2bf_cvt(hnew);
    }
  };

  for (int st = 0; st < 8; ++st){
#pragma unroll
    for (int q=0; q<4; ++q){
      float2 xv = *(const float2*)&xs[(w*16 + u*4 + q)*20 + st*2];
      xq0[q] = xv.x; xq1[q] = xv.y;
    }
    if (st > 0){
      short8 a0 = *(short8*)&hb[c*72 + u*8];
      short8 a1 = *(short8*)&hb[c*72 + 32 + u*8];
      f32x4 zz = {0.f,0.f,0.f,0.f};
#pragma unroll
      for (int gt = 0; gt < 4; ++gt){
        const unsigned short* pr = &whh[(gt*16+c)*72 + u*8];
        const unsigned short* pz = &whh[((4+gt)*16+c)*72 + u*8];
        const unsigned short* pq = &whh[((8+gt)*16+c)*72 + u*8];
        f32x4 aR = __builtin_amdgcn_mfma_f32_16x16x32_bf16(a0, *(const short8*)pr, zz, 0,0,0);
        aR = __builtin_amdgcn_mfma_f32_16x16x32_bf16(a1, *(const short8*)(pr+32), aR, 0,0,0);
        f32x4 aZ = __builtin_amdgcn_mfma_f32_16x16x32_bf16(a0, *(const short8*)pz, zz, 0,0,0);
        aZ = __builtin_amdgcn_mfma_f32_16x16x32_bf16(a1, *(const short8*)(pz+32), aZ, 0,0,0);
        f32x4 aN = __builtin_amdgcn_mfma_f32_16x16x32_bf16(a0, *(const short8*)pq, zz, 0,0,0);
        aN = __builtin_amdgcn_mfma_f32_16x16x32_bf16(a1, *(const short8*)(pq+32), aN, 0,0,0);
        gates(gt, aR, aZ, aN);
      }
    } else {
      f32x4 zz = {0.f,0.f,0.f,0.f};
#pragma unroll
      for (int gt = 0; gt < 4; ++gt) gates(gt, zz, zz, zz);
    }
  }
  __syncthreads();

  // ---- sector pooling ----
  if (lt < 64){
    int n = lt;
    float m   = nmask[(size_t)b*64 + n];
    float ang = rang[(size_t)b*64 + n];
    float tx = ttraj[(size_t)b*16 + 14], ty = ttraj[(size_t)b*16 + 15];
    float px = xs[n*20+14], py = xs[n*20+15];
    float vx = px - xs[n*20+12], vy = py - xs[n*20+13];
    float dx = px - tx, dy = py - ty;
    float dist = __builtin_amdgcn_sqrtf(dx*dx + dy*dy);
    int sid = (int)(ang / 0.78539816339744830962f);
    sid = sid < 0 ? 0 : (sid > 7 ? 7 : sid);
    bool valid = m > 0.0f;
    float wv = valid ? __builtin_amdgcn_exp2f(dist * -0.14426950408889634f) : 0.0f;
    wm[n*8 + sid] = wv;
    dv[n]      = valid ? dist : 0.0f;
    dv[64+n]   = valid ? vx   : 0.0f;
    dv[128+n]  = valid ? vy   : 0.0f;
    sidv[n]    = valid ? (float)sid : -1.0f;
  }
  __syncthreads();
  if (lt < 8){
    int s = lt;
    float cnt=0.f, sd=0.f, sx=0.f, sy=0.f, sw=0.f;
    for (int n=0; n<64; ++n){
      if (sidv[n] == (float)s){
        cnt += 1.f; sd += dv[n]; sx += dv[64+n]; sy += dv[128+n]; sw += wm[n*8+s];
      }
    }
    float inv = (cnt > 0.f) ? __builtin_amdgcn_rcpf(cnt) : 0.f;
    sect[s*8+0] = cnt;
    sect[s*8+1] = sd * inv;
    sect[s*8+2] = sx * inv;
    sect[s*8+3] = sy * inv;
    sect[s*8+4] = __builtin_amdgcn_rcpf(sw + 1e-8f);
  }
  __syncthreads();
#pragma unroll
  for (int rep = 0; rep < 2; ++rep){
    int p = lt + rep*256;
    int s = p >> 6, h = p & 63;
    float a = 0.f;
    for (int n = 0; n < 64; ++n){
      float wmv = wm[n*8 + s];
      float nf  = bf2f(hall[(n>>4)*1152 + (n&15)*72 + h]);
      a += wmv * nf;
    }
    sf[((size_t)b*8 + s)*96 + 4 + h] = (unsigned short)f2bf_cvt(a * sect[s*8+4]);
  }
  if (lt < 32){
    int s = lt >> 2, cc = lt & 3;
    sf[((size_t)b*8 + s)*96 + cc] = (unsigned short)f2bf_cvt(sect[s*8+cc]);
  }
  if (lt < 224){
    int s = lt / 28, cc = 68 + lt % 28;
    sf[((size_t)b*8 + s)*96 + cc] = 0;
  }
}

// ---------------- target GRU: 128 blocks x 256 thr (4 waves) ----------------
// Wave w owns hidden slice [w*32, w*32+32); B-frags register-resident.
// whhT_b is PRESCALED (r,z rows *SGC; n rows *THC).
__global__ __launch_bounds__(256) void k_gru_t(
    const float* __restrict__ ttraj,
    const float* __restrict__ Wih_t, const float* __restrict__ bih_t, const float* __restrict__ bhh_t,
    const unsigned short* __restrict__ wgt,      // whhT_b [384][128] @0
    unsigned short* __restrict__ combined)       // [2048][1152] bf16
{
  __shared__ char smem[9728];
  const int tid = threadIdx.x, w = tid >> 6, u = (tid >> 4) & 3, c = tid & 15;
  unsigned short* hb0 = (unsigned short*)smem;             // [16][136]
  unsigned short* hb1 = (unsigned short*)(smem + 4352);    // [16][136]
  float* xs = (float*)(smem + 8704);                       // [16][16]

  xs[tid] = ttraj[(size_t)blockIdx.x*256 + tid];

  int ntg[6];
  ntg[0] = 2*w; ntg[1] = 2*w+1;
  ntg[2] = 8+2*w; ntg[3] = 9+2*w;
  ntg[4] = 16+2*w; ntg[5] = 17+2*w;

  short8 Bf[6][4];
#pragma unroll
  for (int lt2 = 0; lt2 < 6; ++lt2){
    const unsigned short* wp = wgt + (ntg[lt2]*16 + c)*128 + u*8;
#pragma unroll
    for (int kk = 0; kk < 4; ++kk)
      Bf[lt2][kk] = *(const short8*)(wp + kk*32);
  }

  float Wr0[2],Wr1[2],BR[2],Wz0[2],Wz1[2],BZ[2],Wn0[2],Wn1[2],BI[2],BH[2];
#pragma unroll
  for (int gt = 0; gt < 2; ++gt){
    int g = w*32 + gt*16 + c;
    Wr0[gt]=Wih_t[g*2]*SGC;        Wr1[gt]=Wih_t[g*2+1]*SGC;        BR[gt]=(bih_t[g]+bhh_t[g])*SGC;
    Wz0[gt]=Wih_t[(128+g)*2]*SGC;  Wz1[gt]=Wih_t[(128+g)*2+1]*SGC;  BZ[gt]=(bih_t[128+g]+bhh_t[128+g])*SGC;
    Wn0[gt]=Wih_t[(256+g)*2]*THC;  Wn1[gt]=Wih_t[(256+g)*2+1]*THC;  BI[gt]=bih_t[256+g]*THC; BH[gt]=bhh_t[256+g]*THC;
  }
  float hcur[2][4];
#pragma unroll
  for (int gt=0; gt<2; ++gt)
#pragma unroll
    for (int q=0; q<4; ++q) hcur[gt][q] = 0.0f;
  __syncthreads();

  for (int st = 0; st < 8; ++st){
    unsigned short* rbuf = (st & 1) ? hb0 : hb1;
    unsigned short* wbuf = (st & 1) ? hb1 : hb0;
    f32x4 acc[6];
    if (st > 0){
      short8 a0 = *(short8*)&rbuf[c*136 + u*8];
      short8 a1 = *(short8*)&rbuf[c*136 + 32 + u*8];
      short8 a2 = *(short8*)&rbuf[c*136 + 64 + u*8];
      short8 a3 = *(short8*)&rbuf[c*136 + 96 + u*8];
#pragma unroll
      for (int lt2 = 0; lt2 < 6; ++lt2){
        f32x4 t = {0.f,0.f,0.f,0.f};
        t = __builtin_amdgcn_mfma_f32_16x16x32_bf16(a0, Bf[lt2][0], t, 0,0,0);
        t = __builtin_amdgcn_mfma_f32_16x16x32_bf16(a1, Bf[lt2][1], t, 0,0,0);
        t = __builtin_amdgcn_mfma_f32_16x16x32_bf16(a2, Bf[lt2][2], t, 0,0,0);
        acc[lt2] = __builtin_amdgcn_mfma_f32_16x16x32_bf16(a3, Bf[lt2][3], t, 0,0,0);
      }
    } else {
#pragma unroll
      for (int lt2 = 0; lt2 < 6; ++lt2) acc[lt2] = (f32x4){0.f,0.f,0.f,0.f};
    }
#pragma unroll
    for (int gt = 0; gt < 2; ++gt){
#pragma unroll
      for (int q = 0; q < 4; ++q){
        int sq = u*4 + q;
        float x0 = xs[sq*16 + st*2], x1 = xs[sq*16 + st*2 + 1];
        float rp = __builtin_fmaf(Wr0[gt], x0, __builtin_fmaf(Wr1[gt], x1, acc[gt][q] + BR[gt]));
        float zp = __builtin_fmaf(Wz0[gt], x0, __builtin_fmaf(Wz1[gt], x1, acc[2+gt][q] + BZ[gt]));
        float r = __builtin_amdgcn_rcpf(1.0f + __builtin_amdgcn_exp2f(rp));
        float z = __builtin_amdgcn_rcpf(1.0f + __builtin_amdgcn_exp2f(zp));
        float hnv = acc[4+gt][q] + BH[gt];
        float pn = __builtin_fmaf(Wn0[gt], x0, __builtin_fmaf(Wn1[gt], x1, __builtin_fmaf(r, hnv, BI[gt])));
        float E = __builtin_amdgcn_exp2f(pn);
        float n = __builtin_fmaf(-2.0f, __builtin_amdgcn_rcpf(E + 1.0f), 1.0f);
        float hnew = __builtin_fmaf(z, hcur[gt][q] - n, n);
        hcur[gt][q] = hnew;
        if (st < 7){
          wbuf[sq*136 + w*32 + gt*16 + c] = (unsigned short)f2bf_cvt(hnew);
        } else {
          int row = blockIdx.x*16 + sq;
          combined[(size_t)row*1152 + w*32 + gt*16 + c] = (unsigned short)f2bf_cvt(hnew);
        }
      }
    }
    if (st < 7) __syncthreads();
  }
}

// ---------------- MLP1/MLP2 over (b,s) rows: sf -> enc part of combined ----------------
__global__ __launch_bounds__(256) void k_mlp12(
    const unsigned short* __restrict__ sf,    // [16384][96]
    const unsigned short* __restrict__ wgt,
    const float* __restrict__ b1, const float* __restrict__ b2,
    unsigned short* __restrict__ combined)
{
  __shared__ char smem[18432];
  unsigned short* hb = (unsigned short*)smem + (threadIdx.x >> 6) * 2176;  // [16][136]/wave
  float* b1s = (float*)(smem + 17408);
  float* b2s = b1s + 128;
  const unsigned short* w1b = wgt + 49152;
  const unsigned short* w2b = wgt + 61440;
  const int tid = threadIdx.x, w = tid >> 6, u = (tid >> 4) & 3, c = tid & 15;
  if (tid < 128){ b1s[tid] = b1[tid]; b2s[tid] = b2[tid]; }
  __syncthreads();
  const int rowb = blockIdx.x * 64 + w * 16;

  f32x4 acc[8];
#pragma unroll
  for (int nt=0; nt<8; ++nt) acc[nt] = (f32x4){0.f,0.f,0.f,0.f};
#pragma unroll
  for (int kc=0; kc<3; ++kc){
    short8 a = *(const short8*)&sf[(size_t)(rowb + c)*96 + kc*32 + u*8];
#pragma unroll
    for (int nt=0; nt<8; ++nt){
      short8 bb = *(const short8*)&w1b[(nt*16+c)*96 + kc*32 + u*8];
      acc[nt] = __builtin_amdgcn_mfma_f32_16x16x32_bf16(a, bb, acc[nt], 0,0,0);
    }
  }
#pragma unroll
  for (int nt=0; nt<8; ++nt){
    float bias = b1s[nt*16+c];
#pragma unroll
    for (int q=0; q<4; ++q){
      float v = acc[nt][q] + bias; v = v > 0.f ? v : 0.f;
      hb[(u*4+q)*136 + nt*16 + c] = (unsigned short)f2bf_cvt(v);
    }
  }
  f32x4 acc2[8];
#pragma unroll
  for (int nt=0; nt<8; ++nt) acc2[nt] = (f32x4){0.f,0.f,0.f,0.f};
#pragma unroll
  for (int kc=0; kc<4; ++kc){
    short8 a = *(short8*)&hb[c*136 + kc*32 + u*8];
#pragma unroll
    for (int nt=0; nt<8; ++nt){
      short8 bb = *(const short8*)&w2b[(nt*16+c)*128 + kc*32 + u*8];
      acc2[nt] = __builtin_amdgcn_mfma_f32_16x16x32_bf16(a, bb, acc2[nt], 0,0,0);
    }
  }
#pragma unroll
  for (int nt=0; nt<8; ++nt){
    float bias = b2s[nt*16+c];
#pragma unroll
    for (int q=0; q<4; ++q){
      float v = acc2[nt][q] + bias; v = v > 0.f ? v : 0.f;
      int r = rowb + u*4 + q;
      combined[(size_t)(r >> 3)*1152 + 128 + (r & 7)*128 + nt*16 + c] = (unsigned short)f2bf_cvt(v);
    }
  }
}

// ---------------- head v2: 128 blocks x 256 thr (4 waves) ----------------
__global__ __launch_bounds__(256) void k_head(
    const unsigned short* __restrict__ combined,
    const unsigned short* __restrict__ wgt,
    const float* __restrict__ bf1, const float* __restrict__ bf2, const float* __restrict__ bf3,
    const float* __restrict__ lng, const float* __restrict__ lnb,
    float* __restrict__ out)
{
  __shared__ char smem[15104];
  const int tid = threadIdx.x, w = tid >> 6, u = (tid >> 4) & 3, c = tid & 15;
  unsigned short* f1b = (unsigned short*)smem;                 // [16][264]
  unsigned short* f2b = (unsigned short*)(smem + 8448);        // [16][136]
  float* bf1s = (float*)(smem + 12800); float* bf2s = (float*)(smem + 13824);
  float* bf3s = (float*)(smem + 14336);
  float* lngs = (float*)(smem + 14592); float* lnbs = (float*)(smem + 14848);
  const unsigned short* wf1b = wgt + 77824;
  const unsigned short* wf2b = wgt + 372736;
  const unsigned short* wf3b = wgt + 405504;
  bf1s[tid] = bf1[tid];
  if (tid < 128) bf2s[tid] = bf2[tid];
  if (tid < 64){ bf3s[tid] = bf3[tid]; lngs[tid] = lng[tid]; lnbs[tid] = lnb[tid]; }
  __syncthreads();
  const int rowb = blockIdx.x * 16;

  f32x4 acc[4];
#pragma unroll
  for (int i=0; i<4; ++i) acc[i] = (f32x4){0.f,0.f,0.f,0.f};
#pragma unroll 4
  for (int kc=0; kc<36; ++kc){
    short8 a = *(const short8*)&combined[(size_t)(rowb + c)*1152 + kc*32 + u*8];
#pragma unroll
    for (int i=0; i<4; ++i){
      int nt = w*4 + i;
      short8 bb = *(const short8*)&wf1b[(size_t)(nt*16+c)*1152 + kc*32 + u*8];
      acc[i] = __builtin_amdgcn_mfma_f32_16x16x32_bf16(a, bb, acc[i], 0,0,0);
    }
  }
#pragma unroll
  for (int i=0; i<4; ++i){
    int nt = w*4 + i;
    float bias = bf1s[nt*16+c];
#pragma unroll
    for (int q=0; q<4; ++q){
      float v = acc[i][q] + bias; v = v > 0.f ? v : 0.f;
      f1b[(u*4+q)*264 + nt*16 + c] = (unsigned short)f2bf_cvt(v);
    }
  }
  __syncthreads();

  f32x4 acc2[2];
#pragma unroll
  for (int i=0; i<2; ++i) acc2[i] = (f32x4){0.f,0.f,0.f,0.f};
#pragma unroll
  for (int kc=0; kc<8; ++kc){
    short8 a = *(short8*)&f1b[c*264 + kc*32 + u*8];
#pragma unroll
    for (int i=0; i<2; ++i){
      int nt = w*2 + i;
      short8 bb = *(const short8*)&wf2b[(nt*16+c)*256 + kc*32 + u*8];
      acc2[i] = __builtin_amdgcn_mfma_f32_16x16x32_bf16(a, bb, acc2[i], 0,0,0);
    }
  }
#pragma unroll
  for (int i=0; i<2; ++i){
    int nt = w*2 + i;
    float bias = bf2s[nt*16+c];
#pragma unroll
    for (int q=0; q<4; ++q){
      float v = acc2[i][q] + bias; v = v > 0.f ? v : 0.f;
      f2b[(u*4+q)*136 + nt*16 + c] = (unsigned short)f2bf_cvt(v);
    }
  }
  __syncthreads();

  f32x4 acc3[4];
#pragma unroll
  for (int nt=0; nt<4; ++nt) acc3[nt] = (f32x4){0.f,0.f,0.f,0.f};
#pragma unroll
  for (int kc=0; kc<4; ++kc){
    short8 a = *(short8*)&f2b[c*136 + kc*32 + u*8];
#pragma unroll
    for (int nt=0; nt<4; ++nt){
      short8 bb = *(const short8*)&wf3b[(nt*16+c)*128 + kc*32 + u*8];
      acc3[nt] = __builtin_amdgcn_mfma_f32_16x16x32_bf16(a, bb, acc3[nt], 0,0,0);
    }
  }
  if (w == 0){
    float v[4][4];
#pragma unroll
    for (int nt=0; nt<4; ++nt){
      float bias = bf3s[nt*16+c];
#pragma unroll
      for (int q=0; q<4; ++q){
        float t = acc3[nt][q] + bias; v[nt][q] = t > 0.f ? t : 0.f;
      }
    }
#pragma unroll
    for (int q=0; q<4; ++q){
      float p = v[0][q] + v[1][q] + v[2][q] + v[3][q];
      p += __shfl_xor(p, 1); p += __shfl_xor(p, 2); p += __shfl_xor(p, 4); p += __shfl_xor(p, 8);
      float mu = p * 0.015625f;
      float d0 = v[0][q]-mu, d1 = v[1][q]-mu, d2 = v[2][q]-mu, d3 = v[3][q]-mu;
      float p2 = d0*d0 + d1*d1 + d2*d2 + d3*d3;
      p2 += __shfl_xor(p2, 1); p2 += __shfl_xor(p2, 2); p2 += __shfl_xor(p2, 4); p2 += __shfl_xor(p2, 8);
      float rstd = __builtin_amdgcn_rsqf(p2 * 0.015625f + 1e-5f);
      int row = rowb + u*4 + q;
#pragma unroll
      for (int nt=0; nt<4; ++nt){
        int col = nt*16 + c;
        out[(size_t)row*64 + col] = (v[nt][q] - mu) * rstd * lngs[col] + lnbs[col];
      }
    }
  }
}

extern "C" void kernel_launch(void* const* d_in, const int* in_sizes, int n_in,
                              void* d_out, int out_size, void* d_ws, size_t ws_size,
                              hipStream_t stream)
{
  const float* ttraj = (const float*)d_in[0];
  const float* ntraj = (const float*)d_in[1];
  const float* rang  = (const float*)d_in[2];
  const float* nmask = (const float*)d_in[3];
  const float* Wih_t = (const float*)d_in[4];
  const float* Whh_t = (const float*)d_in[5];
  const float* bih_t = (const float*)d_in[6];
  const float* bhh_t = (const float*)d_in[7];
  const float* Wih_n = (const float*)d_in[8];
  const float* Whh_n = (const float*)d_in[9];
  const float* bih_n = (const float*)d_in[10];
  const float* bhh_n = (const float*)d_in[11];
  const float* W1  = (const float*)d_in[12];
  const float* b1  = (const float*)d_in[13];
  const float* W2  = (const float*)d_in[14];
  const float* b2  = (const float*)d_in[15];
  const float* Wf1 = (const float*)d_in[16];
  const float* bf1 = (const float*)d_in[17];
  const float* Wf2 = (const float*)d_in[18];
  const float* bf2 = (const float*)d_in[19];
  const float* Wf3 = (const float*)d_in[20];
  const float* bf3 = (const float*)d_in[21];
  const float* lng = (const float*)d_in[22];
  const float* lnb = (const float*)d_in[23];

  char* ws = (char*)d_ws;
  unsigned short* combined = (unsigned short*)ws;                  // [2048][1152] bf16
  unsigned short* sf       = (unsigned short*)(ws + 5242880);      // [16384][96] bf16
  unsigned short* wgt      = (unsigned short*)(ws + 8388608);      // bf16 weights

  hipLaunchKernelGGL(k_prep, dim3(1664), dim3(256), 0, stream,
                     Whh_t, W1, W2, Wf1, Wf2, Wf3, Whh_n, wgt);
  hipLaunchKernelGGL(k_gru_n, dim3(1024), dim3(512), 0, stream,
                     ttraj, ntraj, rang, nmask, Wih_n, bih_n, bhh_n, wgt, sf);
  hipLaunchKernelGGL(k_gru_t, dim3(128), dim3(256), 0, stream,
                     ttraj, Wih_t, bih_t, bhh_t, wgt, combined);
  hipLaunchKernelGGL(k_mlp12, dim3(256), dim3(256), 0, stream, sf, wgt, b1, b2, combined);
  hipLaunchKernelGGL(k_head, dim3(128), dim3(256), 0, stream,
                     combined, wgt, bf1, bf2, bf3, lng, lnb, (float*)d_out);
}